// Round 4
// baseline (773.252 us; speedup 1.0000x reference)
//
#include <hip/hip_runtime.h>
#include <hip/hip_bf16.h>

typedef __bf16 bf16;
typedef __attribute__((ext_vector_type(4))) __bf16 bf16x4;
typedef __attribute__((ext_vector_type(8))) __bf16 bf16x8;
typedef __attribute__((ext_vector_type(4))) float f32x4;

#define MFMA(a,b,c) __builtin_amdgcn_mfma_f32_16x16x32_bf16(a,b,c,0,0,0)

// ---- convert x (f32 -> bf16), 4 elements/thread ----
__global__ __launch_bounds__(256) void convert_x_kernel(const float* __restrict__ x,
                                                        bf16* __restrict__ xb) {
    int i = blockIdx.x * 256 + threadIdx.x;
    float4 v = ((const float4*)x)[i];
    bf16x4 o = { (bf16)v.x, (bf16)v.y, (bf16)v.z, (bf16)v.w };
    ((bf16x4*)xb)[i] = o;
}

// ---- transpose + convert one 768x768 weight: Wt[n][k] = (bf16)W[k][n] ----
__global__ __launch_bounds__(1024) void convert_w_kernel(const float* __restrict__ W,
                                                         bf16* __restrict__ Wt) {
    __shared__ float tile[32][33];
    int k0 = blockIdx.x * 32, n0 = blockIdx.y * 32;
    int tx = threadIdx.x & 31, ty = threadIdx.x >> 5;
    tile[ty][tx] = W[(k0 + ty) * 768 + n0 + tx];
    __syncthreads();
    Wt[(n0 + ty) * 768 + k0 + tx] = (bf16)tile[tx][ty];
}

// ---- C = A[M,768] @ Bt[N,768]^T, 128x128 tile, 4 waves (2x2), 4x4 frags/wave ----
// mode 0: q (scale 0.125, head layout [b,h,n,d] bf16)
// mode 1: k (head layout bf16)
// mode 2: v (transposed head layout [b,h,d,n] bf16)
// mode 3: f32 flat [8192,768] to d_out
__global__ __launch_bounds__(256) void gemm_kernel(const bf16* __restrict__ A,
                                                   const bf16* __restrict__ Bt,
                                                   void* __restrict__ dst, int mode) {
    __shared__ bf16 As[128][40];   // stride 40: staging writes 2-way, frag reads 2-way (b64 pairs)
    __shared__ bf16 Bs[128][40];
    const int K = 768;
    int m0 = blockIdx.x * 128, n0 = blockIdx.y * 128;
    int tid = threadIdx.x, lane = tid & 63, w = tid >> 6;
    int wr = w >> 1, wc = w & 1;
    int fr = lane & 15, fg = lane >> 4;
    int srow = tid >> 2, sch = (tid & 3) * 8;
    f32x4 acc[4][4] = {};
    for (int k0 = 0; k0 < K; k0 += 32) {
        __syncthreads();
        *(bf16x8*)&As[srow][sch]      = *(const bf16x8*)&A[(size_t)(m0 + srow) * K + k0 + sch];
        *(bf16x8*)&As[srow + 64][sch] = *(const bf16x8*)&A[(size_t)(m0 + srow + 64) * K + k0 + sch];
        *(bf16x8*)&Bs[srow][sch]      = *(const bf16x8*)&Bt[(size_t)(n0 + srow) * K + k0 + sch];
        *(bf16x8*)&Bs[srow + 64][sch] = *(const bf16x8*)&Bt[(size_t)(n0 + srow + 64) * K + k0 + sch];
        __syncthreads();
        bf16x8 af[4], bfr[4];
        #pragma unroll
        for (int i = 0; i < 4; i++) af[i]  = *(const bf16x8*)&As[wr*64 + i*16 + fr][fg*8];
        #pragma unroll
        for (int j = 0; j < 4; j++) bfr[j] = *(const bf16x8*)&Bs[wc*64 + j*16 + fr][fg*8];
        #pragma unroll
        for (int i = 0; i < 4; i++)
            #pragma unroll
            for (int j = 0; j < 4; j++)
                acc[i][j] = MFMA(af[i], bfr[j], acc[i][j]);
    }
    #pragma unroll
    for (int i = 0; i < 4; i++)
    #pragma unroll
    for (int j = 0; j < 4; j++)
    #pragma unroll
    for (int r = 0; r < 4; r++) {
        int grow = m0 + wr*64 + i*16 + fg*4 + r;   // C/D: row=(l>>4)*4+r
        int gcol = n0 + wc*64 + j*16 + fr;          //      col=l&15
        float v = acc[i][j][r];
        if (mode == 3) {
            ((float*)dst)[(size_t)grow * 768 + gcol] = v;
        } else {
            int b = grow >> 10, np = grow & 1023;
            int h = gcol >> 6, dd = gcol & 63;
            bf16* o = (bf16*)dst;
            if (mode == 0)      o[((size_t)(b*12 + h)*1024 + np)*64 + dd] = (bf16)(v * 0.125f);
            else if (mode == 1) o[((size_t)(b*12 + h)*1024 + np)*64 + dd] = (bf16)v;
            else                o[((size_t)(b*12 + h)*64 + dd)*1024 + np] = (bf16)v;
        }
    }
}

// ---- fused per-head attention v2: scores in registers via swapped QK^T ----
// grid (96 heads, 64 q-slabs of 16), 256 threads (4 waves); wave w owns keys [w*256, w*256+256)
// lane (fr=l&15, fg=l>>4): holds S[key = w*256 + j*16 + fg*4 + r][query = q0+fr] in s[j][r]
__global__ __launch_bounds__(256) void attn_kernel(const bf16* __restrict__ qb,
                                                   const bf16* __restrict__ kb,
                                                   const bf16* __restrict__ vt,
                                                   const float* __restrict__ bias,
                                                   float* __restrict__ attn,
                                                   bf16* __restrict__ Ob) {
    __shared__ bf16 P[16 * 1024];       // 32 KB, 16B-chunk XOR swizzle on (row&7)
    __shared__ float red[2][4][16];     // [max|sum][wave][query]
    int bh = blockIdx.x, q0 = blockIdx.y * 16;
    int tid = threadIdx.x, lane = tid & 63, w = tid >> 6;
    int fr = lane & 15, fg = lane >> 4;
    const bf16* qp = qb + (size_t)bh * 65536;
    const bf16* kp = kb + (size_t)bh * 65536;
    const bf16* vp = vt + (size_t)bh * 65536;
    bf16x8 qa0 = *(const bf16x8*)&qp[(q0 + fr) * 64 + fg * 8];
    bf16x8 qa1 = *(const bf16x8*)&qp[(q0 + fr) * 64 + 32 + fg * 8];
    // phase 1: S^T = K@Q^T + bias, scores stay in registers
    f32x4 s[16];
    #pragma unroll
    for (int j = 0; j < 16; j++) {
        int key0 = w * 256 + j * 16;
        bf16x8 kf0 = *(const bf16x8*)&kp[(key0 + fr) * 64 + fg * 8];
        bf16x8 kf1 = *(const bf16x8*)&kp[(key0 + fr) * 64 + 32 + fg * 8];
        f32x4 a = {};
        a = MFMA(kf0, qa0, a);           // D[key][query]: col=query=fr, row=key=fg*4+r
        a = MFMA(kf1, qa1, a);
        f32x4 bv = *(const f32x4*)&bias[(q0 + fr) * 1024 + key0 + fg * 4];
        s[j] = a + bv;
    }
    // phase 2a: global max for query fr
    float mx = -1e30f;
    #pragma unroll
    for (int j = 0; j < 16; j++)
        mx = fmaxf(fmaxf(fmaxf(mx, s[j][0]), fmaxf(s[j][1], s[j][2])), s[j][3]);
    mx = fmaxf(mx, __shfl_xor(mx, 16));
    mx = fmaxf(mx, __shfl_xor(mx, 32));
    if (lane < 16) red[0][w][lane] = mx;
    __syncthreads();
    mx = fmaxf(fmaxf(red[0][0][fr], red[0][1][fr]), fmaxf(red[0][2][fr], red[0][3][fr]));
    // phase 2b: exp + sum
    float sum = 0.f;
    #pragma unroll
    for (int j = 0; j < 16; j++) {
        s[j][0] = __expf(s[j][0] - mx); s[j][1] = __expf(s[j][1] - mx);
        s[j][2] = __expf(s[j][2] - mx); s[j][3] = __expf(s[j][3] - mx);
        sum += s[j][0] + s[j][1] + s[j][2] + s[j][3];
    }
    sum += __shfl_xor(sum, 16);
    sum += __shfl_xor(sum, 32);
    if (lane < 16) red[1][w][lane] = sum;
    __syncthreads();
    float tot = (red[1][0][fr] + red[1][1][fr]) + (red[1][2][fr] + red[1][3][fr]);
    float rcp = 1.f / tot;
    // phase 2c: write attn (f32, from registers) + P (bf16, swizzled LDS)
    float* arow = attn + ((size_t)bh * 1024 + q0 + fr) * 1024;
    #pragma unroll
    for (int j = 0; j < 16; j++) {
        int key = w * 256 + j * 16 + fg * 4;
        f32x4 p = s[j] * rcp;
        *(f32x4*)&arow[key] = p;
        bf16x4 pb = { (bf16)p[0], (bf16)p[1], (bf16)p[2], (bf16)p[3] };
        int chunk = key >> 3;                      // 16B (8 bf16) granule
        *(bf16x4*)&P[fr * 1024 + ((chunk ^ (fr & 7)) << 3) + (key & 7)] = pb;
    }
    __syncthreads();
    // phase 3: O[16][64] = P @ V; wave w -> d cols [w*16, w*16+16)
    f32x4 oacc = {};
    #pragma unroll
    for (int kk = 0; kk < 32; kk++) {
        int k0e = kk * 32 + fg * 8;
        int chunk = k0e >> 3;                      // = kk*4 + fg
        bf16x8 pa = *(const bf16x8*)&P[fr * 1024 + ((chunk ^ (fr & 7)) << 3)];
        bf16x8 vb = *(const bf16x8*)&vp[(w * 16 + fr) * 1024 + k0e];
        oacc = MFMA(pa, vb, oacc);
    }
    int b = bh / 12, h = bh % 12;
    #pragma unroll
    for (int r = 0; r < 4; r++) {
        int row = fg * 4 + r;
        Ob[((size_t)b * 1024 + q0 + row) * 768 + h * 64 + w * 16 + fr] = (bf16)oacc[r];
    }
}

extern "C" void kernel_launch(void* const* d_in, const int* in_sizes, int n_in,
                              void* d_out, int out_size, void* d_ws, size_t ws_size,
                              hipStream_t stream) {
    const float* x    = (const float*)d_in[0];
    const float* Wq   = (const float*)d_in[1];
    const float* Wk   = (const float*)d_in[2];
    const float* Wv   = (const float*)d_in[3];
    const float* Wp   = (const float*)d_in[4];
    const float* bias = (const float*)d_in[5];
    char* ws = (char*)d_ws;
    // ws layout (bytes): x_bf 12.58M | Wt x4 4.72M | q 12.58M | k 12.58M | vT 12.58M | O 12.58M  (~67.6 MB)
    bf16* xb  = (bf16*)(ws + 0);
    bf16* wt  = (bf16*)(ws + 12582912);
    bf16* qbp = (bf16*)(ws + 17301504);
    bf16* kbp = (bf16*)(ws + 29884416);
    bf16* vtp = (bf16*)(ws + 42467328);
    bf16* obp = (bf16*)(ws + 55050240);
    float* out0 = (float*)d_out;
    float* attn = out0 + 6291456;   // outputs concatenated: out [8,1024,768] then attn [8,12,1024,1024]

    convert_x_kernel<<<6144, 256, 0, stream>>>(x, xb);
    const float* Wsrc[4] = {Wq, Wk, Wv, Wp};
    for (int i = 0; i < 4; i++)
        convert_w_kernel<<<dim3(24,24), 1024, 0, stream>>>(Wsrc[i], wt + (size_t)i*589824);
    gemm_kernel<<<dim3(64,6), 256, 0, stream>>>(xb, wt + 0*589824, qbp, 0);
    gemm_kernel<<<dim3(64,6), 256, 0, stream>>>(xb, wt + 1*589824, kbp, 1);
    gemm_kernel<<<dim3(64,6), 256, 0, stream>>>(xb, wt + 2*589824, vtp, 2);
    attn_kernel<<<dim3(96,64), 256, 0, stream>>>(qbp, kbp, vtp, bias, attn, obp);
    gemm_kernel<<<dim3(64,6), 256, 0, stream>>>(obp, wt + 3*589824, out0, 3);
}

// Round 7
// 631.527 us; speedup vs baseline: 1.2244x; 1.2244x over previous
//
#include <hip/hip_runtime.h>
#include <hip/hip_bf16.h>

typedef __bf16 bf16;
typedef __attribute__((ext_vector_type(4))) __bf16 bf16x4;
typedef __attribute__((ext_vector_type(8))) __bf16 bf16x8;
typedef __attribute__((ext_vector_type(4))) float f32x4;

#define MFMA(a,b,c) __builtin_amdgcn_mfma_f32_16x16x32_bf16(a,b,c,0,0,0)

// Packed layouts (bh = b*12+h, tok = token within batch 0..1023, d = dim 0..63):
//  QP/KP: elem = ((bh*64 + tok>>4)*8 + (d>>3))*128 + (tok&15)*8 + (d&7)
//  VP:    elem = ((bh*4 + (d>>4))*32 + (tok>>5))*512 + ((tok>>3)&3)*128 + (d&15)*8 + (tok&7)
//  biasP: f32 idx = ((qs*64 + kb)*256) + ((k>>2)&3)*64 + (q&15)*4 + (k&3)   [qs=q>>4, kb=k>>4]

// ---- convert x (f32 -> bf16) ----
__global__ __launch_bounds__(256) void convert_x_kernel(const float* __restrict__ x,
                                                        bf16* __restrict__ xb) {
    int i = blockIdx.x * 256 + threadIdx.x;
    float4 v = ((const float4*)x)[i];
    bf16x4 o = { (bf16)v.x, (bf16)v.y, (bf16)v.z, (bf16)v.w };
    ((bf16x4*)xb)[i] = o;
}

// ---- transpose + convert one 768x768 weight: Wt[n][k] = (bf16)W[k][n] ----
__global__ __launch_bounds__(1024) void convert_w_kernel(const float* __restrict__ W,
                                                         bf16* __restrict__ Wt) {
    __shared__ float tile[32][33];
    int k0 = blockIdx.x * 32, n0 = blockIdx.y * 32;
    int tx = threadIdx.x & 31, ty = threadIdx.x >> 5;
    tile[ty][tx] = W[(k0 + ty) * 768 + n0 + tx];
    __syncthreads();
    Wt[(n0 + ty) * 768 + k0 + tx] = (bf16)tile[tx][ty];
}

// ---- pack bias into biasP fragment order ----
__global__ __launch_bounds__(256) void bias_pack_kernel(const float* __restrict__ bias,
                                                        float* __restrict__ biasP) {
    int t = blockIdx.x * 256 + threadIdx.x;
    int fr = t & 15, fg = (t >> 4) & 3, kb = (t >> 6) & 63, qs = t >> 12;
    float4 v = *(const float4*)&bias[(qs * 16 + fr) * 1024 + kb * 16 + fg * 4];
    *(float4*)&biasP[t * 4] = v;
}

// ---- Q/K GEMM: swapped MFMA -> D[feature][token]; direct packed coalesced stores ----
// grid (64, 12): n0 in [0,768) = Q (scale 0.125), [768,1536) = K
__global__ __launch_bounds__(256) void gemm_qk(const bf16* __restrict__ A,
                                               const bf16* __restrict__ Bt,
                                               bf16* __restrict__ QP,
                                               bf16* __restrict__ KP) {
    __shared__ bf16 As[128][40];
    __shared__ bf16 Bs[128][40];
    const int K = 768;
    int m0 = blockIdx.x * 128, n0 = blockIdx.y * 128;
    int tid = threadIdx.x, lane = tid & 63, w = tid >> 6;
    int wr = w >> 1, wc = w & 1;
    int fr = lane & 15, fg = lane >> 4;
    int srow = tid >> 2, sch = (tid & 3) * 8;
    f32x4 acc[4][4] = {};
    for (int k0 = 0; k0 < K; k0 += 32) {
        __syncthreads();
        *(bf16x8*)&As[srow][sch]      = *(const bf16x8*)&A[(size_t)(m0 + srow) * K + k0 + sch];
        *(bf16x8*)&As[srow + 64][sch] = *(const bf16x8*)&A[(size_t)(m0 + srow + 64) * K + k0 + sch];
        *(bf16x8*)&Bs[srow][sch]      = *(const bf16x8*)&Bt[(size_t)(n0 + srow) * K + k0 + sch];
        *(bf16x8*)&Bs[srow + 64][sch] = *(const bf16x8*)&Bt[(size_t)(n0 + srow + 64) * K + k0 + sch];
        __syncthreads();
        bf16x8 af[4], bfr[4];
        #pragma unroll
        for (int i = 0; i < 4; i++) af[i]  = *(const bf16x8*)&As[wr*64 + i*16 + fr][fg*8];
        #pragma unroll
        for (int j = 0; j < 4; j++) bfr[j] = *(const bf16x8*)&Bs[wc*64 + j*16 + fr][fg*8];
        #pragma unroll
        for (int i = 0; i < 4; i++)
            #pragma unroll
            for (int j = 0; j < 4; j++)
                acc[i][j] = MFMA(bfr[j], af[i], acc[i][j]);   // swapped: D[feat fg*4+r][tok fr]
    }
    // epilogue: lane holds features d0+fg*4+{0..3} of token tok0+fr -> one bf16x4 store
    const int mat = (n0 >= 768);
    bf16* __restrict__ dst = mat ? KP : QP;
    const float qscale = mat ? 1.0f : 0.125f;
    int fq_base = (n0 - mat * 768) + wc * 64;
    int t_wave  = m0 + wr * 64;
    int lofs = (fg >> 1) * 128 + fr * 8 + (fg & 1) * 4;
    #pragma unroll
    for (int i = 0; i < 4; i++) {
        int tok0 = t_wave + i * 16;
        int b = tok0 >> 10, ntok = tok0 & 1023;
        #pragma unroll
        for (int j = 0; j < 4; j++) {
            int f0 = fq_base + j * 16;
            int bh = b * 12 + (f0 >> 6), d0 = f0 & 63;
            size_t base = ((size_t)((bh * 64 + (ntok >> 4)) * 8 + (d0 >> 3))) * 128;
            bf16x4 v = { (bf16)(acc[i][j][0] * qscale), (bf16)(acc[i][j][1] * qscale),
                         (bf16)(acc[i][j][2] * qscale), (bf16)(acc[i][j][3] * qscale) };
            *(bf16x4*)&dst[base + lofs] = v;
        }
    }
}

// ---- V GEMM: normal MFMA -> D[token][feature]; direct packed coalesced stores ----
// grid (64, 6)
__global__ __launch_bounds__(256) void gemm_v(const bf16* __restrict__ A,
                                              const bf16* __restrict__ Bt,
                                              bf16* __restrict__ VP) {
    __shared__ bf16 As[128][40];
    __shared__ bf16 Bs[128][40];
    const int K = 768;
    int m0 = blockIdx.x * 128, n0 = blockIdx.y * 128;
    int tid = threadIdx.x, lane = tid & 63, w = tid >> 6;
    int wr = w >> 1, wc = w & 1;
    int fr = lane & 15, fg = lane >> 4;
    int srow = tid >> 2, sch = (tid & 3) * 8;
    f32x4 acc[4][4] = {};
    for (int k0 = 0; k0 < K; k0 += 32) {
        __syncthreads();
        *(bf16x8*)&As[srow][sch]      = *(const bf16x8*)&A[(size_t)(m0 + srow) * K + k0 + sch];
        *(bf16x8*)&As[srow + 64][sch] = *(const bf16x8*)&A[(size_t)(m0 + srow + 64) * K + k0 + sch];
        *(bf16x8*)&Bs[srow][sch]      = *(const bf16x8*)&Bt[(size_t)(n0 + srow) * K + k0 + sch];
        *(bf16x8*)&Bs[srow + 64][sch] = *(const bf16x8*)&Bt[(size_t)(n0 + srow + 64) * K + k0 + sch];
        __syncthreads();
        bf16x8 af[4], bfr[4];
        #pragma unroll
        for (int i = 0; i < 4; i++) af[i]  = *(const bf16x8*)&As[wr*64 + i*16 + fr][fg*8];
        #pragma unroll
        for (int j = 0; j < 4; j++) bfr[j] = *(const bf16x8*)&Bs[wc*64 + j*16 + fr][fg*8];
        #pragma unroll
        for (int i = 0; i < 4; i++)
            #pragma unroll
            for (int j = 0; j < 4; j++)
                acc[i][j] = MFMA(af[i], bfr[j], acc[i][j]);   // D[tok fg*4+r][feat fr]
    }
    // epilogue: lane holds tokens tok0+fg*4+{0..3} of feature f0+fr -> one bf16x4 store
    int t_wave = m0 + wr * 64;
    int lofs = (fg >> 1) * 128 + fr * 8 + (fg & 1) * 4;
    #pragma unroll
    for (int i = 0; i < 4; i++) {
        int tok0 = t_wave + i * 16;
        int b = tok0 >> 10, ntok = tok0 & 1023;
        #pragma unroll
        for (int j = 0; j < 4; j++) {
            int f0 = n0 + wc * 64 + j * 16;
            int bh = b * 12 + (f0 >> 6), d0 = f0 & 63;
            size_t base = ((size_t)((bh * 4 + (d0 >> 4)) * 32 + (ntok >> 5))) * 512
                        + ((ntok >> 3) & 3) * 128;
            bf16x4 v = { (bf16)acc[i][j][0], (bf16)acc[i][j][1],
                         (bf16)acc[i][j][2], (bf16)acc[i][j][3] };
            *(bf16x4*)&VP[base + lofs] = v;
        }
    }
}

// ---- output projection GEMM: out = O[8192,768] @ Wp^T, f32 out ----
__global__ __launch_bounds__(256) void gemm_out(const bf16* __restrict__ A,
                                                const bf16* __restrict__ Bt,
                                                float* __restrict__ dst) {
    __shared__ bf16 As[128][40];
    __shared__ bf16 Bs[128][40];
    const int K = 768;
    int m0 = blockIdx.x * 128, n0 = blockIdx.y * 128;
    int tid = threadIdx.x, lane = tid & 63, w = tid >> 6;
    int wr = w >> 1, wc = w & 1;
    int fr = lane & 15, fg = lane >> 4;
    int srow = tid >> 2, sch = (tid & 3) * 8;
    f32x4 acc[4][4] = {};
    for (int k0 = 0; k0 < K; k0 += 32) {
        __syncthreads();
        *(bf16x8*)&As[srow][sch]      = *(const bf16x8*)&A[(size_t)(m0 + srow) * K + k0 + sch];
        *(bf16x8*)&As[srow + 64][sch] = *(const bf16x8*)&A[(size_t)(m0 + srow + 64) * K + k0 + sch];
        *(bf16x8*)&Bs[srow][sch]      = *(const bf16x8*)&Bt[(size_t)(n0 + srow) * K + k0 + sch];
        *(bf16x8*)&Bs[srow + 64][sch] = *(const bf16x8*)&Bt[(size_t)(n0 + srow + 64) * K + k0 + sch];
        __syncthreads();
        bf16x8 af[4], bfr[4];
        #pragma unroll
        for (int i = 0; i < 4; i++) af[i]  = *(const bf16x8*)&As[wr*64 + i*16 + fr][fg*8];
        #pragma unroll
        for (int j = 0; j < 4; j++) bfr[j] = *(const bf16x8*)&Bs[wc*64 + j*16 + fr][fg*8];
        #pragma unroll
        for (int i = 0; i < 4; i++)
            #pragma unroll
            for (int j = 0; j < 4; j++)
                acc[i][j] = MFMA(af[i], bfr[j], acc[i][j]);
    }
    #pragma unroll
    for (int i = 0; i < 4; i++)
    #pragma unroll
    for (int j = 0; j < 4; j++)
    #pragma unroll
    for (int r = 0; r < 4; r++) {
        int grow = m0 + wr*64 + i*16 + fg*4 + r;
        int gcol = n0 + wc*64 + j*16 + fr;
        dst[(size_t)grow * 768 + gcol] = acc[i][j][r];
    }
}

// ---- fused attention: packed 1-segment loads, coalesced attn writes ----
// grid (64 qslabs, 96 heads), 4 waves; wave w owns key-blocks w*16..w*16+15 and V d-block w
__global__ __launch_bounds__(256) void attn_kernel(const bf16* __restrict__ QP,
                                                   const bf16* __restrict__ KP,
                                                   const bf16* __restrict__ VP,
                                                   const float* __restrict__ biasP,
                                                   float* __restrict__ attn,
                                                   bf16* __restrict__ Ob) {
    __shared__ bf16 P[16 * 1024];       // normalized probs, 16B-granule XOR swizzle on (row&7)
    __shared__ float red[2][4][16];     // [max|sum][wave][query]
    int qs = blockIdx.x, bh = blockIdx.y, q0 = qs * 16;
    int tid = threadIdx.x, lane = tid & 63, w = tid >> 6;
    int fr = lane & 15, fg = lane >> 4;
    const bf16*  qbase = QP + (size_t)(bh * 64 + qs) * 1024;
    const bf16*  kbase = KP + (size_t)bh * 65536;
    const bf16*  vbase = VP + (size_t)(bh * 4 + w) * 16384;
    const float* bbase = biasP + (size_t)qs * 16384;
    bf16x8 qa0 = *(const bf16x8*)&qbase[lane * 8];
    bf16x8 qa1 = *(const bf16x8*)&qbase[512 + lane * 8];
    // phase 1: S^T = K@Q^T + bias; lane holds s[j][r] = S[key=kb*16+fg*4+r][query=q0+fr]
    f32x4 s[16];
    #pragma unroll
    for (int j = 0; j < 16; j++) {
        int kb = w * 16 + j;
        bf16x8 kf0 = *(const bf16x8*)&kbase[kb * 1024 + lane * 8];
        bf16x8 kf1 = *(const bf16x8*)&kbase[kb * 1024 + 512 + lane * 8];
        f32x4 a = {};
        a = MFMA(kf0, qa0, a);
        a = MFMA(kf1, qa1, a);
        f32x4 bv = *(const f32x4*)&bbase[kb * 256 + lane * 4];
        s[j] = a + bv;
    }
    // phase 2a: global max per query fr
    float mx = -1e30f;
    #pragma unroll
    for (int j = 0; j < 16; j++)
        mx = fmaxf(fmaxf(fmaxf(mx, s[j][0]), fmaxf(s[j][1], s[j][2])), s[j][3]);
    mx = fmaxf(mx, __shfl_xor(mx, 16));
    mx = fmaxf(mx, __shfl_xor(mx, 32));
    if (lane < 16) red[0][w][lane] = mx;
    __syncthreads();
    mx = fmaxf(fmaxf(red[0][0][fr], red[0][1][fr]), fmaxf(red[0][2][fr], red[0][3][fr]));
    // phase 2b: exp + sum
    float sum = 0.f;
    #pragma unroll
    for (int j = 0; j < 16; j++) {
        s[j][0] = __expf(s[j][0] - mx); s[j][1] = __expf(s[j][1] - mx);
        s[j][2] = __expf(s[j][2] - mx); s[j][3] = __expf(s[j][3] - mx);
        sum += s[j][0] + s[j][1] + s[j][2] + s[j][3];
    }
    sum += __shfl_xor(sum, 16);
    sum += __shfl_xor(sum, 32);
    if (lane < 16) red[1][w][lane] = sum;
    __syncthreads();
    float tot = (red[1][0][fr] + red[1][1][fr]) + (red[1][2][fr] + red[1][3][fr]);
    float rcp = 1.f / tot;
    // phase 2c: normalized P -> swizzled LDS (bf16)
    #pragma unroll
    for (int j = 0; j < 16; j++) {
        int key = w * 256 + j * 16 + fg * 4;
        f32x4 p = s[j] * rcp;
        bf16x4 pb = { (bf16)p[0], (bf16)p[1], (bf16)p[2], (bf16)p[3] };
        int chunk = key >> 3;
        *(bf16x4*)&P[fr * 1024 + ((chunk ^ (fr & 7)) << 3) + (key & 7)] = pb;
    }
    __syncthreads();
    // attn write pass: wave w owns rows w*4..w*4+3; 1KB-contiguous f32x4 stores
    float* abase = attn + ((size_t)bh * 1024 + q0) * 1024;
    #pragma unroll
    for (int rr = 0; rr < 4; rr++) {
        int row = w * 4 + rr;
        float* arow = abase + (size_t)row * 1024;
        #pragma unroll
        for (int c = 0; c < 4; c++) {
            int g = c * 32 + (lane >> 1);
            bf16x4 pb = *(const bf16x4*)&P[row * 1024 + ((g ^ (row & 7)) << 3) + (lane & 1) * 4];
            f32x4 o = { (float)pb[0], (float)pb[1], (float)pb[2], (float)pb[3] };
            *(f32x4*)&arow[c * 256 + lane * 4] = o;
        }
    }
    // phase 3: O[16][64] = P @ V; wave w -> d cols [w*16, w*16+16)
    f32x4 oacc = {};
    #pragma unroll
    for (int kk = 0; kk < 32; kk++) {
        bf16x8 pa = *(const bf16x8*)&P[fr * 1024 + (((kk * 4 + fg) ^ (fr & 7)) << 3)];
        bf16x8 vb = *(const bf16x8*)&vbase[kk * 512 + lane * 8];
        oacc = MFMA(pa, vb, oacc);
    }
    int b = bh / 12, h = bh % 12;
    #pragma unroll
    for (int r = 0; r < 4; r++) {
        int row = fg * 4 + r;
        Ob[((size_t)b * 1024 + q0 + row) * 768 + h * 64 + w * 16 + fr] = (bf16)oacc[r];
    }
}

extern "C" void kernel_launch(void* const* d_in, const int* in_sizes, int n_in,
                              void* d_out, int out_size, void* d_ws, size_t ws_size,
                              hipStream_t stream) {
    const float* x    = (const float*)d_in[0];
    const float* Wq   = (const float*)d_in[1];
    const float* Wk   = (const float*)d_in[2];
    const float* Wv   = (const float*)d_in[3];
    const float* Wp   = (const float*)d_in[4];
    const float* bias = (const float*)d_in[5];
    char* ws = (char*)d_ws;
    // ws layout (59.2 MB total, < 67.6 MB proven in r1/r4):
    //   xb/obp (aliased; xb dead before attn writes obp) | wt x4 | QP | KP | VP | biasP
    bf16*  xb  = (bf16*)(ws + 0);
    bf16*  obp = (bf16*)(ws + 0);            // alias: stream-ordered kernels serialize
    bf16*  wt  = (bf16*)(ws + 12582912);
    bf16*  QPb = (bf16*)(ws + 17301504);
    bf16*  KPb = (bf16*)(ws + 29884416);
    bf16*  VPb = (bf16*)(ws + 42467328);
    float* bP  = (float*)(ws + 55050240);
    float* out0 = (float*)d_out;
    float* attn = out0 + 6291456;   // outputs: out [8,1024,768] then attn [8,12,1024,1024]

    convert_x_kernel<<<6144, 256, 0, stream>>>(x, xb);
    const float* Wsrc[4] = {Wq, Wk, Wv, Wp};
    for (int i = 0; i < 4; i++)
        convert_w_kernel<<<dim3(24,24), 1024, 0, stream>>>(Wsrc[i], wt + (size_t)i*589824);
    bias_pack_kernel<<<1024, 256, 0, stream>>>(bias, bP);
    gemm_qk<<<dim3(64,12), 256, 0, stream>>>(xb, wt, QPb, KPb);
    gemm_v<<<dim3(64,6), 256, 0, stream>>>(xb, wt + 2*589824, VPb);
    attn_kernel<<<dim3(64,96), 256, 0, stream>>>(QPb, KPb, VPb, bP, attn, obp);
    gemm_out<<<dim3(64,6), 256, 0, stream>>>(obp, wt + 3*589824, out0);
}